// Round 8
// baseline (3946.666 us; speedup 1.0000x reference)
//
#include <hip/hip_runtime.h>
#include <hip/hip_bf16.h>

__global__ void IGMC_15247133901635_kernel() {}

#define cG 5
#define cN 50000
#define cE 250000
#define cB 50
#define cL 200
#define cD 64
#define cR 5
#define cNR 250000
#define cGB 500

// ---------- per-graph prep: zero accumulator + counts, node class ----------
__global__ void k_prep(const float* xg, int* cls, int* cnt, float* hacc) {
  int i = blockIdx.x * 256 + threadIdx.x;  // grid = 6250*256 = cN*32
  hacc[i] = 0.0f;
  if (i < cNR) cnt[i] = 0;
  if (i < cN) {
    int c = 0;
    if (xg[i * 4 + 1] == 1.0f) c = 1;
    else if (xg[i * 4 + 2] == 1.0f) c = 2;
    else if (xg[i * 4 + 3] == 1.0f) c = 3;
    cls[i] = c;
  }
}

__global__ void k_histg(const int* eid, const int* etg, int* cnt) {
  int e = blockIdx.x * 256 + threadIdx.x;
  if (e < cE) atomicAdd(&cnt[eid[e] * cR + etg[e]], 1);
}

__global__ void k_zeroh(float* h) {
  h[blockIdx.x * 256 + threadIdx.x] = 0.0f;  // grid covers cN*32
}

// ---------- RGCN layer 0: one-hot input -> message is a table row ----------
__global__ void k_edge0(const int* eis, const int* eid, const int* etg,
                        const int* cls, const int* cnt,
                        const float* basis0, const float* comp0, float* acc) {
  __shared__ float sW[640];  // [r][c][o] : 5*4*32
  int t = threadIdx.x;
  for (int idx = t; idx < 640; idx += 256) {
    int r = idx / 128, rem = idx - r * 128;  // rem = c*32+o
    sW[idx] = comp0[r * 2] * basis0[rem] + comp0[r * 2 + 1] * basis0[128 + rem];
  }
  __syncthreads();
  long long i = (long long)blockIdx.x * 256 + t;  // grid = 31250*256 = cE*32
  int e = (int)(i >> 5), li = (int)(i & 31);
  int src = eis[e], dst = eid[e], r = etg[e];
  float inv = 1.0f / (float)cnt[dst * cR + r];
  float m = sW[(r * 4 + cls[src]) * 32 + li] * inv;
  atomicAdd(&acc[(long long)dst * 32 + li], m);
}

// ---------- RGCN layers 1..3: h[src] @ W_r scatter ----------
__global__ void k_edgeR(const int* eis, const int* eid, const int* etg,
                        const float* hin, const int* cnt,
                        const float* basis, const float* comp, float* acc) {
  __shared__ float sW[5120];  // [r][i][o] : 5*32*32
  int t = threadIdx.x;
  for (int idx = t; idx < 5120; idx += 256) {
    int r = idx / 1024, rem = idx - r * 1024;
    sW[idx] = comp[r * 2] * basis[rem] + comp[r * 2 + 1] * basis[1024 + rem];
  }
  __syncthreads();
  long long i = (long long)blockIdx.x * 256 + t;  // grid = 31250*256
  int e = (int)(i >> 5), li = (int)(i & 31);
  int src = eis[e], dst = eid[e], r = etg[e];
  const float* hp = hin + (long long)src * 32;
  const float* Wp = sW + r * 1024;
  float m = 0.0f;
  for (int ii = 0; ii < 32; ii++) m += hp[ii] * Wp[ii * 32 + li];
  m *= 1.0f / (float)cnt[dst * cR + r];
  atomicAdd(&acc[(long long)dst * 32 + li], m);
}

__global__ void k_fin0(float* hacc, const int* cls, const float* root0,
                       const float* bias0) {
  int i = blockIdx.x * 256 + threadIdx.x;  // cN*32
  int n = i >> 5, o = i & 31;
  hacc[i] = tanhf(hacc[i] + root0[cls[n] * 32 + o] + bias0[o]);
}

__global__ void k_finR(float* hacc, const float* hin, const float* root,
                       const float* bias) {
  int i = blockIdx.x * 256 + threadIdx.x;  // cN*32
  int n = i >> 5, o = i & 31;
  const float* hp = hin + (long long)n * 32;
  float a = hacc[i];
  for (int k = 0; k < 32; k++) a += hp[k] * root[k * 32 + o];
  hacc[i] = tanhf(a + bias[o]);
}

// ---------- ordered compaction: first cB nodes with x[:,c]==1 ----------
__global__ void k_uidx(const float* x, int* uidx) {
  int g = blockIdx.x >> 1, c = blockIdx.x & 1;
  __shared__ int sFlag[256];
  __shared__ int sBase;
  int t = threadIdx.x;
  if (t < cB) uidx[(g * 2 + c) * cB + t] = 0;  // fill_value = 0
  if (t == 0) sBase = 0;
  __syncthreads();
  for (int chunk = 0; chunk < cN; chunk += 256) {
    int n = chunk + t;
    sFlag[t] = (n < cN && x[((long long)g * cN + n) * 4 + c] == 1.0f) ? 1 : 0;
    __syncthreads();
    if (t == 0) {
      int base = sBase;
      for (int t2 = 0; t2 < 256; t2++) {
        if (sFlag[t2]) {
          if (base < cB) uidx[(g * 2 + c) * cB + base] = chunk + t2;
          base++;
        }
      }
      sBase = base;
    }
    __syncthreads();
    if (sBase >= cB) break;
  }
}

__global__ void k_extract(const float* h, const int* uidx, float* xlist, int g, int layer) {
  int i = blockIdx.x * 256 + threadIdx.x;  // 2*cB*32 = 3200
  if (i >= 2 * cB * 32) return;
  int o = i & 31;
  int rest = i >> 5;
  int b = rest % cB, c = rest / cB;
  int node = uidx[(g * 2 + c) * cB + b];
  xlist[(g * cB + b) * 256 + c * 128 + layer * 32 + o] = h[(long long)node * 32 + o];
}

// ---------- STAM: fused QKV + attention; one block per (seq, head) ----------
__global__ void k_attn2(const int* tt, const float* emb, const float* pos,
                        const float* Qw, const float* Kw, const float* Vw,
                        float* hatt, int gb_base) {
  int gbl = blockIdx.x >> 2, hh = blockIdx.x & 3;
  int gb = gb_base + gbl;
  __shared__ float sW[64 * 48];   // [i][mat*16+dh] for this head
  __shared__ float sQ[200 * 16];
  __shared__ float sK[200 * 16];
  __shared__ float sV[200 * 16];
  __shared__ float sT[4][64];
  int t = threadIdx.x;
  for (int idx = t; idx < 3072; idx += 256) {
    int mat = idx >> 10, rem = idx & 1023;
    int i = rem >> 4, dh = rem & 15;
    const float* W = (mat == 0) ? Qw : ((mat == 1) ? Kw : Vw);
    sW[i * 48 + mat * 16 + dh] = W[i * 64 + hh * 16 + dh];
  }
  __syncthreads();
  // stage A: project 4 rows at a time
  for (int it = 0; it < 50; it++) {
    int r4 = t >> 6, d = t & 63;
    int l = it * 4 + r4;
    int idx = tt[(long long)gb * 200 + l];
    sT[r4][d] = emb[(long long)idx * 64 + d] + pos[l * 64 + d];
    __syncthreads();
    if (t < 192) {
      int rr = t / 48, c48 = t - rr * 48;
      float acc = 0.0f;
      for (int i = 0; i < 64; i++) acc += sT[rr][i] * sW[i * 48 + c48];
      int ll = it * 4 + rr;
      int mat = c48 >> 4, dh = c48 & 15;
      if (mat == 0) sQ[ll * 16 + dh] = acc;
      else if (mat == 1) sK[ll * 16 + dh] = acc;
      else sV[ll * 16 + dh] = acc;
    }
    __syncthreads();
  }
  // stage B: one query row per thread, two-pass softmax
  if (t < 200) {
    float scale = 1.0f / sqrtf(200.0f);
    float q[16];
    for (int dh = 0; dh < 16; dh++) q[dh] = sQ[t * 16 + dh];
    float mx = -1e30f;
    for (int m = 0; m < 200; m++) {
      float s = 0.0f;
      for (int dh = 0; dh < 16; dh++) s += q[dh] * sK[m * 16 + dh];
      s *= scale;
      if (s > mx) mx = s;
    }
    float outv[16];
    for (int dh = 0; dh < 16; dh++) outv[dh] = 0.0f;
    float sum = 0.0f;
    for (int m = 0; m < 200; m++) {
      float s = 0.0f;
      for (int dh = 0; dh < 16; dh++) s += q[dh] * sK[m * 16 + dh];
      float e = expf(s * scale - mx);
      sum += e;
      for (int dh = 0; dh < 16; dh++) outv[dh] += e * sV[m * 16 + dh];
    }
    float inv = 1.0f / sum;
    for (int dh = 0; dh < 16; dh++)
      hatt[((long long)gbl * 200 + t) * 64 + hh * 16 + dh] = outv[dh] * inv;
  }
}

// ---------- STAM: conv1d + residual + L2 norm + tw-softmax + _emb ----------
__global__ void k_convtw(const float* hatt, const int* tt, const int* cen,
                         const float* emb, const float* pos, const float* convW,
                         const float* convb, const float* lab, float* embout,
                         int gb_base) {
  int gbl = blockIdx.x;
  int gb = gb_base + gbl;
  __shared__ float sH[12800];
  __shared__ float sA[200];
  __shared__ float sR1[256];
  __shared__ float sR2[256];
  __shared__ float sW1[64];
  int t = threadIdx.x;
  const float* hb = hatt + (long long)gbl * 12800;
  for (int i = t; i < 12800; i += 256) sH[i] = hb[i];
  if (t < 64) sW1[t] = emb[(long long)cen[gb] * 64 + t];
  __syncthreads();
  int og = t >> 6, d = t & 63;
  for (int round = 0; round < 50; round++) {
    int o = round * 4 + og;
    float conv = 0.0f;
    const float* cw = convW + o * 200;
    for (int l2 = 0; l2 < 200; l2++) conv += cw[l2] * sH[l2 * 64 + d];
    float tval = emb[(long long)tt[(long long)gb * 200 + o] * 64 + d] + pos[o * 64 + d];
    float outv = tval + conv + convb[o] + sH[o * 64 + d];
    sR1[t] = outv * outv;
    sR2[t] = outv * sW1[d];
    __syncthreads();
    if (d == 0) {
      float ss = 0.0f, pw = 0.0f;
      for (int k = 0; k < 64; k++) { ss += sR1[og * 64 + k]; pw += sR2[og * 64 + k]; }
      float dn = sqrtf(ss);
      if (dn < 1e-12f) dn = 1e-12f;
      sA[o] = pw / dn;
    }
    __syncthreads();
  }
  if (t == 0) {
    float mx = -1e30f;
    for (int l = 0; l < 200; l++) if (sA[l] > mx) mx = sA[l];
    float sum = 0.0f;
    for (int l = 0; l < 200; l++) {
      float a = expf(sA[l] - mx) * lab[(long long)gb * 200 + l];
      sA[l] = a;
      sum += a;
    }
    if (sum > 0.0f) {
      float inv = 1.0f / sum;
      for (int l = 0; l < 200; l++) sA[l] *= inv;
    } else {
      for (int l = 0; l < 200; l++) sA[l] = 0.0f;
    }
  }
  __syncthreads();
  if (t < 64) {
    float acc = 0.0f;
    for (int l = 0; l < 200; l++)
      acc += sA[l] * emb[(long long)tt[(long long)gb * 200 + l] * 64 + t];
    embout[(long long)gb * 64 + t] = acc;
  }
}

// ---------- head ----------
__global__ void k_att1(const float* xlist, const float* aw1, const float* ab1,
                       const float* aw2, float* attK) {
  int blk = blockIdx.x;  // b*cG + g
  int b = blk / cG, g = blk - b * cG;
  int j = threadIdx.x;
  __shared__ float sRed[256];
  const float* sub = xlist + (g * cB + b) * 256;
  float acc = ab1[j];
  for (int i = 0; i < 256; i++) acc += sub[i] * aw1[i * 256 + j];
  if (acc < 0.0f) acc = 0.0f;
  sRed[j] = acc * aw2[j];
  __syncthreads();
  if (j == 0) {
    float s = 0.0f;
    for (int k = 0; k < 256; k++) s += sRed[k];
    attK[b * cG + g] = s;
  }
}

__global__ void k_hm(const float* attK, const float* xlist, const float* mw1,
                     const float* mb1, float* metah) {
  int b = blockIdx.x;
  __shared__ float sAgg[256];
  int t = threadIdx.x;
  float a0 = attK[b * 5 + 0], a1 = attK[b * 5 + 1], a2 = attK[b * 5 + 2],
        a3 = attK[b * 5 + 3], a4 = attK[b * 5 + 4];
  float mx = a0;
  if (a1 > mx) mx = a1;
  if (a2 > mx) mx = a2;
  if (a3 > mx) mx = a3;
  if (a4 > mx) mx = a4;
  float e0 = expf(a0 - mx), e1 = expf(a1 - mx), e2 = expf(a2 - mx),
        e3 = expf(a3 - mx), e4 = expf(a4 - mx);
  float s = e0 + e1 + e2 + e3 + e4;
  sAgg[t] = (e0 * xlist[(0 * cB + b) * 256 + t] + e1 * xlist[(1 * cB + b) * 256 + t] +
             e2 * xlist[(2 * cB + b) * 256 + t] + e3 * xlist[(3 * cB + b) * 256 + t] +
             e4 * xlist[(4 * cB + b) * 256 + t]) / s;
  __syncthreads();
  for (int j = t; j < 512; j += 256) {
    float acc = mb1[j];
    for (int i = 0; i < 256; i++) acc += sAgg[i] * mw1[i * 512 + j];
    if (acc < 0.0f) acc = 0.0f;
    metah[b * 512 + j] = acc;
  }
}

__global__ void k_m2(const float* metah, const float* mw2, const float* mb2,
                     const float* xlist, const float* embout, float* xcat) {
  int i = blockIdx.x * 256 + threadIdx.x;  // cB*1920
  if (i >= cB * 1920) return;
  int b = i / 1920, j = i - b * 1920;
  if (j < 1280) {
    float acc = mb2[j];
    const float* mh = metah + b * 512;
    for (int k = 0; k < 512; k++) acc += mh[k] * mw2[k * 1280 + j];
    int g = j >> 8, jj = j & 255;
    xcat[b * 1920 + j] = acc * xlist[(g * cB + b) * 256 + jj];
  } else {
    int jj = j - 1280;
    int g = jj >> 7, r = jj & 127;
    xcat[b * 1920 + j] = embout[(g * 100 + 2 * b + (r >> 6)) * 64 + (r & 63)];
  }
}

__global__ void k_l12(const float* xcat, const float* l1w, const float* l1b,
                      const float* l2w, const float* l2b, float* out) {
  int b = blockIdx.x;
  int t = threadIdx.x;  // 128
  __shared__ float sHH[128];
  float acc = l1b[t];
  const float* xc = xcat + b * 1920;
  for (int i = 0; i < 1920; i++) acc += xc[i] * l1w[i * 128 + t];
  if (acc < 0.0f) acc = 0.0f;
  sHH[t] = acc;
  __syncthreads();
  if (t == 0) {
    float a = 0.0f;
    for (int k = 0; k < 128; k++) a += sHH[k] * l2w[k];
    out[b] = a + l2b[0];
  }
}

extern "C" void kernel_launch(void* const* d_in, const int* in_sizes, int n_in,
                              void* d_out, int out_size, void* d_ws, size_t ws_size,
                              hipStream_t stream) {
  const float* x      = (const float*)d_in[0];
  const int* ei       = (const int*)d_in[1];
  const int* et       = (const int*)d_in[2];
  const int* cen      = (const int*)d_in[3];
  const int* tt       = (const int*)d_in[4];
  const float* lab    = (const float*)d_in[5];
  const float* emb    = (const float*)d_in[6];
  const float* basis0 = (const float*)d_in[7];
  const float* comp0  = (const float*)d_in[8];
  const float* root0  = (const float*)d_in[9];
  const float* bias0  = (const float*)d_in[10];
  const float* basisR = (const float*)d_in[11];
  const float* compR  = (const float*)d_in[12];
  const float* rootR  = (const float*)d_in[13];
  const float* biasR  = (const float*)d_in[14];
  const float* pos    = (const float*)d_in[15];
  const float* Qw     = (const float*)d_in[16];
  const float* Kw     = (const float*)d_in[17];
  const float* Vw     = (const float*)d_in[18];
  const float* convW  = (const float*)d_in[19];
  const float* convb  = (const float*)d_in[20];
  const float* aw1    = (const float*)d_in[21];
  const float* ab1    = (const float*)d_in[22];
  const float* aw2    = (const float*)d_in[23];
  const float* mw1    = (const float*)d_in[24];
  const float* mb1    = (const float*)d_in[25];
  const float* mw2    = (const float*)d_in[26];
  const float* mb2    = (const float*)d_in[27];
  const float* l1w    = (const float*)d_in[28];
  const float* l1b    = (const float*)d_in[29];
  const float* l2w    = (const float*)d_in[30];
  const float* l2b    = (const float*)d_in[31];
  float* out          = (float*)d_out;

  char* p = (char*)d_ws;
  int*   uidx   = (int*)(p);                    //     2,000 B
  int*   clsb   = (int*)(p + 4096);             //   200,000 B
  int*   cnt    = (int*)(p + 208896);           // 1,000,000 B
  float* xlist  = (float*)(p + 1212416);        //   512,000 B
  float* embout = (float*)(p + 1728512);        //   128,000 B
  float* attK   = (float*)(p + 1860608);        //     1,000 B
  float* metah  = (float*)(p + 1864704);        //   102,400 B
  float* xcat   = (float*)(p + 1970176);        //   384,000 B
  char*  arena  = p + 2359296;                  // 12,800,000 B (h_a/h_b | hatt)
  float* h_a    = (float*)(arena);
  float* h_b    = (float*)(arena + 6400000);
  float* hatt   = (float*)(arena);
  (void)in_sizes; (void)n_in; (void)out_size; (void)ws_size;  // total ~15.2 MB

  k_uidx<<<cG * 2, 256, 0, stream>>>(x, uidx);

  for (int g = 0; g < cG; g++) {
    const int* eis = ei + (long long)g * 2 * cE;
    const int* eid = eis + cE;
    const int* etg = et + (long long)g * cE;
    const float* xg = x + (long long)g * cN * 4;
    k_prep<<<6250, 256, 0, stream>>>(xg, clsb, cnt, h_b);
    k_histg<<<977, 256, 0, stream>>>(eid, etg, cnt);
    k_edge0<<<31250, 256, 0, stream>>>(eis, eid, etg, clsb, cnt, basis0, comp0, h_b);
    k_fin0<<<6250, 256, 0, stream>>>(h_b, clsb, root0, bias0);
    k_extract<<<13, 256, 0, stream>>>(h_b, uidx, xlist, g, 0);
    float* hin = h_b;
    float* hacc = h_a;
    for (int l = 0; l < 3; l++) {
      k_zeroh<<<6250, 256, 0, stream>>>(hacc);
      k_edgeR<<<31250, 256, 0, stream>>>(eis, eid, etg, hin, cnt,
                                         basisR + l * 2048, compR + l * 10, hacc);
      k_finR<<<6250, 256, 0, stream>>>(hacc, hin, rootR + l * 1024, biasR + l * 32);
      k_extract<<<13, 256, 0, stream>>>(hacc, uidx, xlist, g, l + 1);
      float* tmp = hin; hin = hacc; hacc = tmp;
    }
  }

  for (int c = 0; c < 2; c++) {
    k_attn2<<<1000, 256, 0, stream>>>(tt, emb, pos, Qw, Kw, Vw, hatt, c * 250);
    k_convtw<<<250, 256, 0, stream>>>(hatt, tt, cen, emb, pos, convW, convb, lab,
                                      embout, c * 250);
  }

  k_att1<<<cB * cG, 256, 0, stream>>>(xlist, aw1, ab1, aw2, attK);
  k_hm<<<cB, 256, 0, stream>>>(attK, xlist, mw1, mb1, metah);
  k_m2<<<375, 256, 0, stream>>>(metah, mw2, mb2, xlist, embout, xcat);
  k_l12<<<cB, 128, 0, stream>>>(xcat, l1w, l1b, l2w, l2b, out);
}

// Round 9
// 2099.125 us; speedup vs baseline: 1.8801x; 1.8801x over previous
//
#include <hip/hip_runtime.h>
#include <hip/hip_bf16.h>

__global__ void IGMC_15247133901635_kernel() {}

#define cG 5
#define cN 50000
#define cE 250000
#define cB 50
#define cL 200
#define cD 64
#define cR 5
#define cNR 250000
#define cGB 500

// ---------- per-graph prep: zero counts + global counter, node class ----------
__global__ void k_prep(const float* xg, int* cls, int* cur, int* gctr) {
  int i = blockIdx.x * 256 + threadIdx.x;  // grid = 977*256 >= cNR
  if (i < cNR) cur[i] = 0;                 // cur doubles as cnt for histogram
  if (i < cN) {
    int c = 0;
    if (xg[i * 4 + 1] == 1.0f) c = 1;
    else if (xg[i * 4 + 2] == 1.0f) c = 2;
    else if (xg[i * 4 + 3] == 1.0f) c = 3;
    cls[i] = c;
  }
  if (i == 0) gctr[0] = 0;
}

__global__ void k_histg(const int* eid, const int* etg, int* cur) {
  int e = blockIdx.x * 256 + threadIdx.x;
  if (e < cE) atomicAdd(&cur[eid[e] * cR + etg[e]], 1);
}

// ---------- build CSR offsets: order-independent block scan ----------
__global__ void k_mkoff(int* cur, int* off, int* gctr) {
  __shared__ int sC[256];
  __shared__ int sO[256];
  __shared__ int sBase;
  int t = threadIdx.x;
  int i = blockIdx.x * 256 + t;
  int c = (i < cNR) ? cur[i] : 0;
  sC[t] = c;
  __syncthreads();
  if (t == 0) {
    int run = 0;
    for (int k = 0; k < 256; k++) { sO[k] = run; run += sC[k]; }
    sBase = atomicAdd(gctr, run);
  }
  __syncthreads();
  if (i < cNR) {
    int v = sBase + sO[t];
    off[i] = v;
    cur[i] = v;   // becomes running cursor; after scatter cur[i] == bin end
  }
}

// perm[pos] = src*4 + cls[src]
__global__ void k_scatter(const int* eis, const int* eid, const int* etg,
                          const int* cls, int* cur, int* perm) {
  int e = blockIdx.x * 256 + threadIdx.x;
  if (e >= cE) return;
  int src = eis[e];
  int bin = eid[e] * cR + etg[e];
  int pos = atomicAdd(&cur[bin], 1);
  perm[pos] = src * 4 + cls[src];
}

// ---------- RGCN layer 0: gather of class-table rows ----------
__global__ void k_gather0(const int* off, const int* cur, const int* perm,
                          const int* cls, const float* basis0, const float* comp0,
                          const float* root0, const float* bias0, float* hout) {
  __shared__ float sW0[640];   // [r][c][o]
  __shared__ float sRt[128];
  __shared__ float sB[32];
  int t = threadIdx.x;
  for (int idx = t; idx < 640; idx += 256) {
    int r = idx / 128, rem = idx - r * 128;
    sW0[idx] = comp0[r * 2] * basis0[rem] + comp0[r * 2 + 1] * basis0[128 + rem];
  }
  if (t < 128) sRt[t] = root0[t];
  if (t < 32) sB[t] = bias0[t];
  __syncthreads();
  int nd = t >> 5, li = t & 31;
  int n = blockIdx.x * 8 + nd;          // grid = 6250 blocks -> 50000 nodes
  int binb = n * cR;
  float tot = 0.0f;
  for (int r = 0; r < cR; r++) {
    int st = off[binb + r], en = cur[binb + r];
    if (en > st) {
      float s = 0.0f;
      for (int j = st; j < en; j++) s += sW0[(r * 4 + (perm[j] & 3)) * 32 + li];
      tot += s / (float)(en - st);
    }
  }
  hout[(long long)n * 32 + li] = tanhf(tot + sRt[cls[n] * 32 + li] + sB[li]);
}

// ---------- RGCN layers 1..3: gather raw h, then z_b @ B_b + h @ root ----------
__global__ void k_gatherR(const int* off, const int* cur, const int* perm,
                          const float* hin, const float* basis, const float* comp,
                          const float* root, const float* bias, float* hout) {
  __shared__ float sB0[1024];
  __shared__ float sB1[1024];
  __shared__ float sRt[1024];
  __shared__ float sZ0[8][32];
  __shared__ float sZ1[8][32];
  __shared__ float sHl[8][32];
  __shared__ float sBias[32];
  int t = threadIdx.x;
  for (int idx = t; idx < 1024; idx += 256) {
    sB0[idx] = basis[idx];
    sB1[idx] = basis[1024 + idx];
    sRt[idx] = root[idx];
  }
  if (t < 32) sBias[t] = bias[t];
  int nd = t >> 5, li = t & 31;
  int n = blockIdx.x * 8 + nd;          // grid = 6250
  sHl[nd][li] = hin[(long long)n * 32 + li];
  int binb = n * cR;
  float z0 = 0.0f, z1 = 0.0f;
  for (int r = 0; r < cR; r++) {
    int st = off[binb + r], en = cur[binb + r];
    if (en > st) {
      float s = 0.0f;
      for (int j = st; j < en; j++) s += hin[(long long)(perm[j] >> 2) * 32 + li];
      float ic = 1.0f / (float)(en - st);
      z0 += comp[r * 2] * s * ic;
      z1 += comp[r * 2 + 1] * s * ic;
    }
  }
  sZ0[nd][li] = z0;
  sZ1[nd][li] = z1;
  __syncthreads();
  float a = sBias[li];
  for (int i = 0; i < 32; i++)
    a += sZ0[nd][i] * sB0[i * 32 + li] + sZ1[nd][i] * sB1[i * 32 + li] +
         sHl[nd][i] * sRt[i * 32 + li];
  hout[(long long)n * 32 + li] = tanhf(a);
}

// ---------- ordered compaction: first cB nodes with x[:,c]==1 ----------
__global__ void k_uidx(const float* x, int* uidx) {
  int g = blockIdx.x >> 1, c = blockIdx.x & 1;
  __shared__ int sFlag[256];
  __shared__ int sBase;
  int t = threadIdx.x;
  if (t < cB) uidx[(g * 2 + c) * cB + t] = 0;
  if (t == 0) sBase = 0;
  __syncthreads();
  for (int chunk = 0; chunk < cN; chunk += 256) {
    int n = chunk + t;
    sFlag[t] = (n < cN && x[((long long)g * cN + n) * 4 + c] == 1.0f) ? 1 : 0;
    __syncthreads();
    if (t == 0) {
      int base = sBase;
      for (int t2 = 0; t2 < 256; t2++) {
        if (sFlag[t2]) {
          if (base < cB) uidx[(g * 2 + c) * cB + base] = chunk + t2;
          base++;
        }
      }
      sBase = base;
    }
    __syncthreads();
    if (sBase >= cB) break;
  }
}

__global__ void k_extract(const float* h, const int* uidx, float* xlist, int g, int layer) {
  int i = blockIdx.x * 256 + threadIdx.x;
  if (i >= 2 * cB * 32) return;
  int o = i & 31;
  int rest = i >> 5;
  int b = rest % cB, c = rest / cB;
  int node = uidx[(g * 2 + c) * cB + b];
  xlist[(g * cB + b) * 256 + c * 128 + layer * 32 + o] = h[(long long)node * 32 + o];
}

// ---------- STAM: fused QKV + attention (padded LDS, online softmax) ----------
__global__ void k_attn2(const int* tt, const float* emb, const float* pos,
                        const float* Qw, const float* Kw, const float* Vw,
                        float* hatt, int gb_base) {
  int gbl = blockIdx.x >> 2, hh = blockIdx.x & 3;
  int gb = gb_base + gbl;
  __shared__ float sW[3072];      // [i][mat*16+dh]
  __shared__ float sQ[3400];      // 200 rows, stride 17
  __shared__ float sK[3400];
  __shared__ float sV[3400];
  __shared__ float sT[4][64];
  int t = threadIdx.x;
  for (int idx = t; idx < 3072; idx += 256) {
    int mat = idx >> 10, rem = idx & 1023;
    int i = rem >> 4, dh = rem & 15;
    const float* W = (mat == 0) ? Qw : ((mat == 1) ? Kw : Vw);
    sW[i * 48 + mat * 16 + dh] = W[i * 64 + hh * 16 + dh];
  }
  __syncthreads();
  // stage A: project 4 rows at a time
  for (int it = 0; it < 50; it++) {
    int r4 = t >> 6, d = t & 63;
    int l = it * 4 + r4;
    int idx = tt[(long long)gb * 200 + l];
    sT[r4][d] = emb[(long long)idx * 64 + d] + pos[l * 64 + d];
    __syncthreads();
    if (t < 192) {
      int rr = t / 48, c48 = t - rr * 48;
      float acc = 0.0f;
      for (int i = 0; i < 64; i++) acc += sT[rr][i] * sW[i * 48 + c48];
      int ll = it * 4 + rr;
      int mat = c48 >> 4, dh = c48 & 15;
      if (mat == 0) sQ[ll * 17 + dh] = acc;
      else if (mat == 1) sK[ll * 17 + dh] = acc;
      else sV[ll * 17 + dh] = acc;
    }
    __syncthreads();
  }
  // stage B: one query row per thread, online softmax (single K/V pass)
  if (t < 200) {
    float scale = 1.0f / sqrtf(200.0f);
    float q[16];
    for (int dh = 0; dh < 16; dh++) q[dh] = sQ[t * 17 + dh];
    float m0 = -1e30f, lsum = 0.0f;
    float ov[16];
    for (int dh = 0; dh < 16; dh++) ov[dh] = 0.0f;
    for (int m = 0; m < 200; m++) {
      float s = 0.0f;
      for (int dh = 0; dh < 16; dh++) s += q[dh] * sK[m * 17 + dh];
      s *= scale;
      if (s > m0) {
        float f = expf(m0 - s);
        lsum *= f;
        for (int dh = 0; dh < 16; dh++) ov[dh] *= f;
        m0 = s;
      }
      float e = expf(s - m0);
      lsum += e;
      for (int dh = 0; dh < 16; dh++) ov[dh] += e * sV[m * 17 + dh];
    }
    float inv = 1.0f / lsum;
    for (int dh = 0; dh < 16; dh++)
      hatt[((long long)gbl * 200 + t) * 64 + hh * 16 + dh] = ov[dh] * inv;
  }
}

// ---------- STAM: conv1d + residual + L2 norm + tw-softmax + _emb ----------
__global__ void k_convtw(const float* hatt, const int* tt, const int* cen,
                         const float* emb, const float* pos, const float* convW,
                         const float* convb, const float* lab, float* embout,
                         int gb_base) {
  int gbl = blockIdx.x;
  int gb = gb_base + gbl;
  __shared__ float sH[12800];
  __shared__ float sCW[800];
  __shared__ float sA[200];
  __shared__ float sR1[256];
  __shared__ float sR2[256];
  __shared__ float sP[256];
  __shared__ float sW1[64];
  int t = threadIdx.x;
  const float* hb = hatt + (long long)gbl * 12800;
  for (int i = t; i < 12800; i += 256) sH[i] = hb[i];
  if (t < 64) sW1[t] = emb[(long long)cen[gb] * 64 + t];
  __syncthreads();
  int og = t >> 6, d = t & 63;
  for (int round = 0; round < 50; round++) {
    for (int idx = t; idx < 800; idx += 256) {
      int row = idx / 200, col = idx - row * 200;
      sCW[idx] = convW[(round * 4 + row) * 200 + col];
    }
    __syncthreads();
    int o = round * 4 + og;
    float conv = 0.0f;
    const float* cw = sCW + og * 200;
    for (int l2 = 0; l2 < 200; l2++) conv += cw[l2] * sH[l2 * 64 + d];
    float tval = emb[(long long)tt[(long long)gb * 200 + o] * 64 + d] + pos[o * 64 + d];
    float outv = tval + conv + convb[o] + sH[o * 64 + d];
    sR1[t] = outv * outv;
    sR2[t] = outv * sW1[d];
    __syncthreads();
    for (int s = 32; s > 0; s >>= 1) {
      if (d < s) { sR1[t] += sR1[t + s]; sR2[t] += sR2[t + s]; }
      __syncthreads();
    }
    if (d == 0) {
      float dn = sqrtf(sR1[t]);
      if (dn < 1e-12f) dn = 1e-12f;
      sA[o] = sR2[t] / dn;
    }
    __syncthreads();
  }
  // parallel softmax * label with renorm
  sP[t] = (t < 200) ? sA[t] : -1e30f;
  __syncthreads();
  for (int s = 128; s > 0; s >>= 1) {
    if (t < s) { float o2 = sP[t + s]; if (o2 > sP[t]) sP[t] = o2; }
    __syncthreads();
  }
  float mx = sP[0];
  __syncthreads();
  float a = 0.0f;
  if (t < 200) {
    a = expf(sA[t] - mx) * lab[(long long)gb * 200 + t];
    sA[t] = a;
  }
  sP[t] = a;
  __syncthreads();
  for (int s = 128; s > 0; s >>= 1) {
    if (t < s) sP[t] += sP[t + s];
    __syncthreads();
  }
  float sum = sP[0];
  __syncthreads();
  if (t < 200) sA[t] = (sum > 0.0f) ? sA[t] / sum : 0.0f;
  __syncthreads();
  // _emb: 4-way parallel over l, then cross-group reduce
  float acc2 = 0.0f;
  for (int l = og * 50; l < og * 50 + 50; l++)
    acc2 += sA[l] * emb[(long long)tt[(long long)gb * 200 + l] * 64 + d];
  sR1[t] = acc2;
  __syncthreads();
  if (t < 64)
    embout[(long long)gb * 64 + t] = sR1[t] + sR1[64 + t] + sR1[128 + t] + sR1[192 + t];
}

// ---------- head ----------
__global__ void k_att1(const float* xlist, const float* aw1, const float* ab1,
                       const float* aw2, float* attK) {
  int blk = blockIdx.x;
  int b = blk / cG, g = blk - b * cG;
  int j = threadIdx.x;
  __shared__ float sRed[256];
  const float* sub = xlist + (g * cB + b) * 256;
  float acc = ab1[j];
  for (int i = 0; i < 256; i++) acc += sub[i] * aw1[i * 256 + j];
  if (acc < 0.0f) acc = 0.0f;
  sRed[j] = acc * aw2[j];
  __syncthreads();
  for (int s = 128; s > 0; s >>= 1) {
    if (j < s) sRed[j] += sRed[j + s];
    __syncthreads();
  }
  if (j == 0) attK[b * cG + g] = sRed[0];
}

__global__ void k_hm(const float* attK, const float* xlist, const float* mw1,
                     const float* mb1, float* metah) {
  int b = blockIdx.x;
  __shared__ float sAgg[256];
  int t = threadIdx.x;
  float a0 = attK[b * 5 + 0], a1 = attK[b * 5 + 1], a2 = attK[b * 5 + 2],
        a3 = attK[b * 5 + 3], a4 = attK[b * 5 + 4];
  float mx = a0;
  if (a1 > mx) mx = a1;
  if (a2 > mx) mx = a2;
  if (a3 > mx) mx = a3;
  if (a4 > mx) mx = a4;
  float e0 = expf(a0 - mx), e1 = expf(a1 - mx), e2 = expf(a2 - mx),
        e3 = expf(a3 - mx), e4 = expf(a4 - mx);
  float s = e0 + e1 + e2 + e3 + e4;
  sAgg[t] = (e0 * xlist[(0 * cB + b) * 256 + t] + e1 * xlist[(1 * cB + b) * 256 + t] +
             e2 * xlist[(2 * cB + b) * 256 + t] + e3 * xlist[(3 * cB + b) * 256 + t] +
             e4 * xlist[(4 * cB + b) * 256 + t]) / s;
  __syncthreads();
  for (int j = t; j < 512; j += 256) {
    float acc = mb1[j];
    for (int i = 0; i < 256; i++) acc += sAgg[i] * mw1[i * 512 + j];
    if (acc < 0.0f) acc = 0.0f;
    metah[b * 512 + j] = acc;
  }
}

__global__ void k_m2(const float* metah, const float* mw2, const float* mb2,
                     const float* xlist, const float* embout, float* xcat) {
  int i = blockIdx.x * 256 + threadIdx.x;
  if (i >= cB * 1920) return;
  int b = i / 1920, j = i - b * 1920;
  if (j < 1280) {
    float acc = mb2[j];
    const float* mh = metah + b * 512;
    for (int k = 0; k < 512; k++) acc += mh[k] * mw2[k * 1280 + j];
    int g = j >> 8, jj = j & 255;
    xcat[b * 1920 + j] = acc * xlist[(g * cB + b) * 256 + jj];
  } else {
    int jj = j - 1280;
    int g = jj >> 7, r = jj & 127;
    xcat[b * 1920 + j] = embout[(g * 100 + 2 * b + (r >> 6)) * 64 + (r & 63)];
  }
}

__global__ void k_l12(const float* xcat, const float* l1w, const float* l1b,
                      const float* l2w, const float* l2b, float* out) {
  int b = blockIdx.x;
  int t = threadIdx.x;  // 128
  __shared__ float sHH[128];
  float acc = l1b[t];
  const float* xc = xcat + b * 1920;
  for (int i = 0; i < 1920; i++) acc += xc[i] * l1w[i * 128 + t];
  if (acc < 0.0f) acc = 0.0f;
  sHH[t] = acc * l2w[t];
  __syncthreads();
  for (int s = 64; s > 0; s >>= 1) {
    if (t < s) sHH[t] += sHH[t + s];
    __syncthreads();
  }
  if (t == 0) out[b] = sHH[0] + l2b[0];
}

extern "C" void kernel_launch(void* const* d_in, const int* in_sizes, int n_in,
                              void* d_out, int out_size, void* d_ws, size_t ws_size,
                              hipStream_t stream) {
  const float* x      = (const float*)d_in[0];
  const int* ei       = (const int*)d_in[1];
  const int* et       = (const int*)d_in[2];
  const int* cen      = (const int*)d_in[3];
  const int* tt       = (const int*)d_in[4];
  const float* lab    = (const float*)d_in[5];
  const float* emb    = (const float*)d_in[6];
  const float* basis0 = (const float*)d_in[7];
  const float* comp0  = (const float*)d_in[8];
  const float* root0  = (const float*)d_in[9];
  const float* bias0  = (const float*)d_in[10];
  const float* basisR = (const float*)d_in[11];
  const float* compR  = (const float*)d_in[12];
  const float* rootR  = (const float*)d_in[13];
  const float* biasR  = (const float*)d_in[14];
  const float* pos    = (const float*)d_in[15];
  const float* Qw     = (const float*)d_in[16];
  const float* Kw     = (const float*)d_in[17];
  const float* Vw     = (const float*)d_in[18];
  const float* convW  = (const float*)d_in[19];
  const float* convb  = (const float*)d_in[20];
  const float* aw1    = (const float*)d_in[21];
  const float* ab1    = (const float*)d_in[22];
  const float* aw2    = (const float*)d_in[23];
  const float* mw1    = (const float*)d_in[24];
  const float* mb1    = (const float*)d_in[25];
  const float* mw2    = (const float*)d_in[26];
  const float* mb2    = (const float*)d_in[27];
  const float* l1w    = (const float*)d_in[28];
  const float* l1b    = (const float*)d_in[29];
  const float* l2w    = (const float*)d_in[30];
  const float* l2b    = (const float*)d_in[31];
  float* out          = (float*)d_out;

  char* p = (char*)d_ws;
  int*   uidx   = (int*)(p);                    //      2,000 B
  int*   clsb   = (int*)(p + 4096);             //    200,000 B
  int*   cur    = (int*)(p + 208896);           //  1,000,000 B (cnt -> cursor -> bin end)
  int*   off    = (int*)(p + 1212416);          //  1,000,000 B
  int*   perm   = (int*)(p + 2215936);          //  1,000,000 B (src*4 + cls)
  int*   gctr   = (int*)(p + 3219456);          //          4 B
  float* xlist  = (float*)(p + 3223552);        //    512,000 B
  float* embout = (float*)(p + 3739648);        //    128,000 B
  float* attK   = (float*)(p + 3870720);        //      1,000 B
  float* metah  = (float*)(p + 3874816);        //    102,400 B
  float* xcat   = (float*)(p + 3981312);        //    384,000 B
  char*  arena  = p + 4369408;                  // 12,800,000 B (h_a/h_b | hatt)
  float* h_a    = (float*)(arena);
  float* h_b    = (float*)(arena + 6400000);
  float* hatt   = (float*)(arena);
  (void)in_sizes; (void)n_in; (void)out_size; (void)ws_size;  // total ~17.2 MB

  k_uidx<<<cG * 2, 256, 0, stream>>>(x, uidx);

  for (int g = 0; g < cG; g++) {
    const int* eis = ei + (long long)g * 2 * cE;
    const int* eid = eis + cE;
    const int* etg = et + (long long)g * cE;
    const float* xg = x + (long long)g * cN * 4;
    // CSR build (per graph, reused across 4 layers)
    k_prep<<<977, 256, 0, stream>>>(xg, clsb, cur, gctr);
    k_histg<<<977, 256, 0, stream>>>(eid, etg, cur);
    k_mkoff<<<977, 256, 0, stream>>>(cur, off, gctr);
    k_scatter<<<977, 256, 0, stream>>>(eis, eid, etg, clsb, cur, perm);
    // layer 0
    k_gather0<<<6250, 256, 0, stream>>>(off, cur, perm, clsb, basis0, comp0,
                                        root0, bias0, h_b);
    k_extract<<<13, 256, 0, stream>>>(h_b, uidx, xlist, g, 0);
    // layers 1..3
    float* hin = h_b;
    float* hou = h_a;
    for (int l = 0; l < 3; l++) {
      k_gatherR<<<6250, 256, 0, stream>>>(off, cur, perm, hin,
                                          basisR + l * 2048, compR + l * 10,
                                          rootR + l * 1024, biasR + l * 32, hou);
      k_extract<<<13, 256, 0, stream>>>(hou, uidx, xlist, g, l + 1);
      float* tmp = hin; hin = hou; hou = tmp;
    }
  }

  for (int c = 0; c < 2; c++) {
    k_attn2<<<1000, 256, 0, stream>>>(tt, emb, pos, Qw, Kw, Vw, hatt, c * 250);
    k_convtw<<<250, 256, 0, stream>>>(hatt, tt, cen, emb, pos, convW, convb, lab,
                                      embout, c * 250);
  }

  k_att1<<<cB * cG, 256, 0, stream>>>(xlist, aw1, ab1, aw2, attK);
  k_hm<<<cB, 256, 0, stream>>>(attK, xlist, mw1, mb1, metah);
  k_m2<<<375, 256, 0, stream>>>(metah, mw2, mb2, xlist, embout, xcat);
  k_l12<<<cB, 128, 0, stream>>>(xcat, l1w, l1b, l2w, l2b, out);
}

// Round 10
// 2065.506 us; speedup vs baseline: 1.9108x; 1.0163x over previous
//
#include <hip/hip_runtime.h>
#include <hip/hip_bf16.h>

__global__ void IGMC_15247133901635_kernel() {}

#define cG 5
#define cN 50000
#define cE 250000
#define cB 50
#define cL 200
#define cD 64
#define cR 5
#define cNR 250000
#define cGB 500

// ---------- per-graph prep: zero counts + global counter, node class ----------
__global__ void k_prep(const float* xg, int* cls, int* cur, int* gctr) {
  int i = blockIdx.x * 256 + threadIdx.x;  // grid = 977*256 >= cNR
  if (i < cNR) cur[i] = 0;                 // cur doubles as cnt for histogram
  if (i < cN) {
    int c = 0;
    if (xg[i * 4 + 1] == 1.0f) c = 1;
    else if (xg[i * 4 + 2] == 1.0f) c = 2;
    else if (xg[i * 4 + 3] == 1.0f) c = 3;
    cls[i] = c;
  }
  if (i == 0) gctr[0] = 0;
}

__global__ void k_histg(const int* eid, const int* etg, int* cur) {
  int e = blockIdx.x * 256 + threadIdx.x;
  if (e < cE) atomicAdd(&cur[eid[e] * cR + etg[e]], 1);
}

// ---------- build CSR offsets: order-independent block scan ----------
__global__ void k_mkoff(int* cur, int* off, int* gctr) {
  __shared__ int sC[256];
  __shared__ int sO[256];
  __shared__ int sBase;
  int t = threadIdx.x;
  int i = blockIdx.x * 256 + t;
  int c = (i < cNR) ? cur[i] : 0;
  sC[t] = c;
  __syncthreads();
  if (t == 0) {
    int run = 0;
    for (int k = 0; k < 256; k++) { sO[k] = run; run += sC[k]; }
    sBase = atomicAdd(gctr, run);
  }
  __syncthreads();
  if (i < cNR) {
    int v = sBase + sO[t];
    off[i] = v;
    cur[i] = v;   // becomes running cursor; after scatter cur[i] == bin end
  }
}

// perm[pos] = src*4 + cls[src]
__global__ void k_scatter(const int* eis, const int* eid, const int* etg,
                          const int* cls, int* cur, int* perm) {
  int e = blockIdx.x * 256 + threadIdx.x;
  if (e >= cE) return;
  int src = eis[e];
  int bin = eid[e] * cR + etg[e];
  int pos = atomicAdd(&cur[bin], 1);
  perm[pos] = src * 4 + cls[src];
}

// ---------- RGCN layer 0: gather of class-table rows ----------
__global__ void k_gather0(const int* off, const int* cur, const int* perm,
                          const int* cls, const float* basis0, const float* comp0,
                          const float* root0, const float* bias0, float* hout) {
  __shared__ float sW0[640];   // [r][c][o]
  __shared__ float sRt[128];
  __shared__ float sB[32];
  int t = threadIdx.x;
  for (int idx = t; idx < 640; idx += 256) {
    int r = idx / 128, rem = idx - r * 128;
    sW0[idx] = comp0[r * 2] * basis0[rem] + comp0[r * 2 + 1] * basis0[128 + rem];
  }
  if (t < 128) sRt[t] = root0[t];
  if (t < 32) sB[t] = bias0[t];
  __syncthreads();
  int nd = t >> 5, li = t & 31;
  int n = blockIdx.x * 8 + nd;          // grid = 6250 blocks -> 50000 nodes
  int binb = n * cR;
  float tot = 0.0f;
  for (int r = 0; r < cR; r++) {
    int st = off[binb + r], en = cur[binb + r];
    if (en > st) {
      float s = 0.0f;
      for (int j = st; j < en; j++) s += sW0[(r * 4 + (perm[j] & 3)) * 32 + li];
      tot += s / (float)(en - st);
    }
  }
  hout[(long long)n * 32 + li] = tanhf(tot + sRt[cls[n] * 32 + li] + sB[li]);
}

// ---------- RGCN layers 1..3: gather raw h, then z_b @ B_b + h @ root ----------
__global__ void k_gatherR(const int* off, const int* cur, const int* perm,
                          const float* hin, const float* basis, const float* comp,
                          const float* root, const float* bias, float* hout) {
  __shared__ float sB0[1024];
  __shared__ float sB1[1024];
  __shared__ float sRt[1024];
  __shared__ float sZ0[8][32];
  __shared__ float sZ1[8][32];
  __shared__ float sHl[8][32];
  __shared__ float sBias[32];
  int t = threadIdx.x;
  for (int idx = t; idx < 1024; idx += 256) {
    sB0[idx] = basis[idx];
    sB1[idx] = basis[1024 + idx];
    sRt[idx] = root[idx];
  }
  if (t < 32) sBias[t] = bias[t];
  int nd = t >> 5, li = t & 31;
  int n = blockIdx.x * 8 + nd;          // grid = 6250
  sHl[nd][li] = hin[(long long)n * 32 + li];
  int binb = n * cR;
  float z0 = 0.0f, z1 = 0.0f;
  for (int r = 0; r < cR; r++) {
    int st = off[binb + r], en = cur[binb + r];
    if (en > st) {
      float s = 0.0f;
      for (int j = st; j < en; j++) s += hin[(long long)(perm[j] >> 2) * 32 + li];
      float ic = 1.0f / (float)(en - st);
      z0 += comp[r * 2] * s * ic;
      z1 += comp[r * 2 + 1] * s * ic;
    }
  }
  sZ0[nd][li] = z0;
  sZ1[nd][li] = z1;
  __syncthreads();
  float a = sBias[li];
  for (int i = 0; i < 32; i++)
    a += sZ0[nd][i] * sB0[i * 32 + li] + sZ1[nd][i] * sB1[i * 32 + li] +
         sHl[nd][i] * sRt[i * 32 + li];
  hout[(long long)n * 32 + li] = tanhf(a);
}

// ---------- ordered compaction: first cB nodes with x[:,c]==1 ----------
__global__ void k_uidx(const float* x, int* uidx) {
  int g = blockIdx.x >> 1, c = blockIdx.x & 1;
  __shared__ int sFlag[256];
  __shared__ int sBase;
  int t = threadIdx.x;
  if (t < cB) uidx[(g * 2 + c) * cB + t] = 0;
  if (t == 0) sBase = 0;
  __syncthreads();
  for (int chunk = 0; chunk < cN; chunk += 256) {
    int n = chunk + t;
    sFlag[t] = (n < cN && x[((long long)g * cN + n) * 4 + c] == 1.0f) ? 1 : 0;
    __syncthreads();
    if (t == 0) {
      int base = sBase;
      for (int t2 = 0; t2 < 256; t2++) {
        if (sFlag[t2]) {
          if (base < cB) uidx[(g * 2 + c) * cB + base] = chunk + t2;
          base++;
        }
      }
      sBase = base;
    }
    __syncthreads();
    if (sBase >= cB) break;
  }
}

__global__ void k_extract(const float* h, const int* uidx, float* xlist, int g, int layer) {
  int i = blockIdx.x * 256 + threadIdx.x;
  if (i >= 2 * cB * 32) return;
  int o = i & 31;
  int rest = i >> 5;
  int b = rest % cB, c = rest / cB;
  int node = uidx[(g * 2 + c) * cB + b];
  xlist[(g * cB + b) * 256 + c * 128 + layer * 32 + o] = h[(long long)node * 32 + o];
}

// ---------- STAM: fused QKV + attention v3 ----------
// float4 LDS rows (stride 5xfloat4), 2 query rows/thread, reg-stationary weights,
// branchless online softmax.
__global__ void k_attn2(const int* tt, const float* emb, const float* pos,
                        const float* Qw, const float* Kw, const float* Vw,
                        float* hatt, int gb_base) {
  int gbl = blockIdx.x >> 2, hh = blockIdx.x & 3;
  int gb = gb_base + gbl;
  __shared__ float4 sQ4[1000];   // 200 rows x 5 float4 (16 used + pad)
  __shared__ float4 sK4[1000];
  __shared__ float4 sV4[1000];
  __shared__ float4 sT4[2][64];  // double-buffered 4x64 row staging
  float* sQ = (float*)sQ4;
  float* sK = (float*)sK4;
  float* sV = (float*)sV4;
  int t = threadIdx.x;
  // stage-A weight column -> registers (t < 192)
  float wreg[64];
  int rr = t / 48, c48 = t - rr * 48;
  if (t < 192) {
    int mat = c48 >> 4, dh = c48 & 15;
    const float* W = (mat == 0) ? Qw : ((mat == 1) ? Kw : Vw);
    const float* wp = W + hh * 16 + dh;
    for (int i = 0; i < 64; i += 4) {
      wreg[i] = wp[i * 64];
      wreg[i + 1] = wp[(i + 1) * 64];
      wreg[i + 2] = wp[(i + 2) * 64];
      wreg[i + 3] = wp[(i + 3) * 64];
    }
  }
  // stage A: project 4 rows/iter; one barrier per iter via double buffer
  int r4 = t >> 6, d = t & 63;
  for (int it = 0; it < 50; it++) {
    int p = it & 1;
    int l4 = it * 4 + r4;
    int idx = tt[(long long)gb * 200 + l4];
    ((float*)sT4)[p * 256 + r4 * 64 + d] =
        emb[(long long)idx * 64 + d] + pos[l4 * 64 + d];
    __syncthreads();
    if (t < 192) {
      const float4* tp = (const float4*)(sT4[p] + rr * 16);
      float acc = 0.0f;
      for (int i4 = 0; i4 < 16; i4++) {
        float4 tv = tp[i4];
        acc += tv.x * wreg[i4 * 4] + tv.y * wreg[i4 * 4 + 1] +
               tv.z * wreg[i4 * 4 + 2] + tv.w * wreg[i4 * 4 + 3];
      }
      int ll = it * 4 + rr;
      int mat = c48 >> 4, dh = c48 & 15;
      if (mat == 0) sQ[ll * 20 + dh] = acc;
      else if (mat == 1) sK[ll * 20 + dh] = acc;
      else sV[ll * 20 + dh] = acc;
    }
  }
  __syncthreads();
  // stage B: thread t < 100 handles query rows t and t+100
  if (t < 100) {
    float scale = 1.0f / sqrtf(200.0f);
    float4 qa0 = sQ4[t * 5], qa1 = sQ4[t * 5 + 1], qa2 = sQ4[t * 5 + 2],
           qa3 = sQ4[t * 5 + 3];
    int t2 = t + 100;
    float4 qb0 = sQ4[t2 * 5], qb1 = sQ4[t2 * 5 + 1], qb2 = sQ4[t2 * 5 + 2],
           qb3 = sQ4[t2 * 5 + 3];
    qa0.x *= scale; qa0.y *= scale; qa0.z *= scale; qa0.w *= scale;
    qa1.x *= scale; qa1.y *= scale; qa1.z *= scale; qa1.w *= scale;
    qa2.x *= scale; qa2.y *= scale; qa2.z *= scale; qa2.w *= scale;
    qa3.x *= scale; qa3.y *= scale; qa3.z *= scale; qa3.w *= scale;
    qb0.x *= scale; qb0.y *= scale; qb0.z *= scale; qb0.w *= scale;
    qb1.x *= scale; qb1.y *= scale; qb1.z *= scale; qb1.w *= scale;
    qb2.x *= scale; qb2.y *= scale; qb2.z *= scale; qb2.w *= scale;
    qb3.x *= scale; qb3.y *= scale; qb3.z *= scale; qb3.w *= scale;
    float m0a = -1e30f, la = 0.0f, m0b = -1e30f, lb = 0.0f;
    float4 oa0 = {0,0,0,0}, oa1 = {0,0,0,0}, oa2 = {0,0,0,0}, oa3 = {0,0,0,0};
    float4 ob0 = {0,0,0,0}, ob1 = {0,0,0,0}, ob2 = {0,0,0,0}, ob3 = {0,0,0,0};
    for (int m = 0; m < 200; m++) {
      float4 k0 = sK4[m * 5], k1 = sK4[m * 5 + 1], k2 = sK4[m * 5 + 2],
             k3 = sK4[m * 5 + 3];
      float sa = qa0.x * k0.x + qa0.y * k0.y + qa0.z * k0.z + qa0.w * k0.w +
                 qa1.x * k1.x + qa1.y * k1.y + qa1.z * k1.z + qa1.w * k1.w +
                 qa2.x * k2.x + qa2.y * k2.y + qa2.z * k2.z + qa2.w * k2.w +
                 qa3.x * k3.x + qa3.y * k3.y + qa3.z * k3.z + qa3.w * k3.w;
      float sb = qb0.x * k0.x + qb0.y * k0.y + qb0.z * k0.z + qb0.w * k0.w +
                 qb1.x * k1.x + qb1.y * k1.y + qb1.z * k1.z + qb1.w * k1.w +
                 qb2.x * k2.x + qb2.y * k2.y + qb2.z * k2.z + qb2.w * k2.w +
                 qb3.x * k3.x + qb3.y * k3.y + qb3.z * k3.z + qb3.w * k3.w;
      float4 v0 = sV4[m * 5], v1 = sV4[m * 5 + 1], v2 = sV4[m * 5 + 2],
             v3 = sV4[m * 5 + 3];
      float na = fmaxf(m0a, sa);
      float fa = expf(m0a - na);
      float ea = expf(sa - na);
      m0a = na;
      la = la * fa + ea;
      oa0.x = oa0.x * fa + ea * v0.x; oa0.y = oa0.y * fa + ea * v0.y;
      oa0.z = oa0.z * fa + ea * v0.z; oa0.w = oa0.w * fa + ea * v0.w;
      oa1.x = oa1.x * fa + ea * v1.x; oa1.y = oa1.y * fa + ea * v1.y;
      oa1.z = oa1.z * fa + ea * v1.z; oa1.w = oa1.w * fa + ea * v1.w;
      oa2.x = oa2.x * fa + ea * v2.x; oa2.y = oa2.y * fa + ea * v2.y;
      oa2.z = oa2.z * fa + ea * v2.z; oa2.w = oa2.w * fa + ea * v2.w;
      oa3.x = oa3.x * fa + ea * v3.x; oa3.y = oa3.y * fa + ea * v3.y;
      oa3.z = oa3.z * fa + ea * v3.z; oa3.w = oa3.w * fa + ea * v3.w;
      float nb = fmaxf(m0b, sb);
      float fb = expf(m0b - nb);
      float eb = expf(sb - nb);
      m0b = nb;
      lb = lb * fb + eb;
      ob0.x = ob0.x * fb + eb * v0.x; ob0.y = ob0.y * fb + eb * v0.y;
      ob0.z = ob0.z * fb + eb * v0.z; ob0.w = ob0.w * fb + eb * v0.w;
      ob1.x = ob1.x * fb + eb * v1.x; ob1.y = ob1.y * fb + eb * v1.y;
      ob1.z = ob1.z * fb + eb * v1.z; ob1.w = ob1.w * fb + eb * v1.w;
      ob2.x = ob2.x * fb + eb * v2.x; ob2.y = ob2.y * fb + eb * v2.y;
      ob2.z = ob2.z * fb + eb * v2.z; ob2.w = ob2.w * fb + eb * v2.w;
      ob3.x = ob3.x * fb + eb * v3.x; ob3.y = ob3.y * fb + eb * v3.y;
      ob3.z = ob3.z * fb + eb * v3.z; ob3.w = ob3.w * fb + eb * v3.w;
    }
    float ia = 1.0f / la, ib = 1.0f / lb;
    oa0.x *= ia; oa0.y *= ia; oa0.z *= ia; oa0.w *= ia;
    oa1.x *= ia; oa1.y *= ia; oa1.z *= ia; oa1.w *= ia;
    oa2.x *= ia; oa2.y *= ia; oa2.z *= ia; oa2.w *= ia;
    oa3.x *= ia; oa3.y *= ia; oa3.z *= ia; oa3.w *= ia;
    ob0.x *= ib; ob0.y *= ib; ob0.z *= ib; ob0.w *= ib;
    ob1.x *= ib; ob1.y *= ib; ob1.z *= ib; ob1.w *= ib;
    ob2.x *= ib; ob2.y *= ib; ob2.z *= ib; ob2.w *= ib;
    ob3.x *= ib; ob3.y *= ib; ob3.z *= ib; ob3.w *= ib;
    float4* outa = (float4*)(hatt + ((long long)gbl * 200 + t) * 64 + hh * 16);
    outa[0] = oa0; outa[1] = oa1; outa[2] = oa2; outa[3] = oa3;
    float4* outb = (float4*)(hatt + ((long long)gbl * 200 + t2) * 64 + hh * 16);
    outb[0] = ob0; outb[1] = ob1; outb[2] = ob2; outb[3] = ob3;
  }
}

// ---------- STAM: conv1d + residual + L2 norm + tw-softmax + _emb ----------
__global__ void k_convtw(const float* hatt, const int* tt, const int* cen,
                         const float* emb, const float* pos, const float* convW,
                         const float* convb, const float* lab, float* embout,
                         int gb_base) {
  int gbl = blockIdx.x;
  int gb = gb_base + gbl;
  __shared__ float sH[12800];
  __shared__ float sCW[800];
  __shared__ float sA[200];
  __shared__ float sR1[256];
  __shared__ float sR2[256];
  __shared__ float sP[256];
  __shared__ float sW1[64];
  int t = threadIdx.x;
  const float* hb = hatt + (long long)gbl * 12800;
  for (int i = t; i < 12800; i += 256) sH[i] = hb[i];
  if (t < 64) sW1[t] = emb[(long long)cen[gb] * 64 + t];
  __syncthreads();
  int og = t >> 6, d = t & 63;
  for (int round = 0; round < 50; round++) {
    for (int idx = t; idx < 800; idx += 256) {
      int row = idx / 200, col = idx - row * 200;
      sCW[idx] = convW[(round * 4 + row) * 200 + col];
    }
    __syncthreads();
    int o = round * 4 + og;
    float conv = 0.0f;
    const float* cw = sCW + og * 200;
    for (int l2 = 0; l2 < 200; l2++) conv += cw[l2] * sH[l2 * 64 + d];
    float tval = emb[(long long)tt[(long long)gb * 200 + o] * 64 + d] + pos[o * 64 + d];
    float outv = tval + conv + convb[o] + sH[o * 64 + d];
    sR1[t] = outv * outv;
    sR2[t] = outv * sW1[d];
    __syncthreads();
    for (int s = 32; s > 0; s >>= 1) {
      if (d < s) { sR1[t] += sR1[t + s]; sR2[t] += sR2[t + s]; }
      __syncthreads();
    }
    if (d == 0) {
      float dn = sqrtf(sR1[t]);
      if (dn < 1e-12f) dn = 1e-12f;
      sA[o] = sR2[t] / dn;
    }
    __syncthreads();
  }
  // parallel softmax * label with renorm
  sP[t] = (t < 200) ? sA[t] : -1e30f;
  __syncthreads();
  for (int s = 128; s > 0; s >>= 1) {
    if (t < s) { float o2 = sP[t + s]; if (o2 > sP[t]) sP[t] = o2; }
    __syncthreads();
  }
  float mx = sP[0];
  __syncthreads();
  float a = 0.0f;
  if (t < 200) {
    a = expf(sA[t] - mx) * lab[(long long)gb * 200 + t];
    sA[t] = a;
  }
  sP[t] = a;
  __syncthreads();
  for (int s = 128; s > 0; s >>= 1) {
    if (t < s) sP[t] += sP[t + s];
    __syncthreads();
  }
  float sum = sP[0];
  __syncthreads();
  if (t < 200) sA[t] = (sum > 0.0f) ? sA[t] / sum : 0.0f;
  __syncthreads();
  // _emb: 4-way parallel over l, then cross-group reduce
  float acc2 = 0.0f;
  for (int l = og * 50; l < og * 50 + 50; l++)
    acc2 += sA[l] * emb[(long long)tt[(long long)gb * 200 + l] * 64 + d];
  sR1[t] = acc2;
  __syncthreads();
  if (t < 64)
    embout[(long long)gb * 64 + t] = sR1[t] + sR1[64 + t] + sR1[128 + t] + sR1[192 + t];
}

// ---------- head ----------
__global__ void k_att1(const float* xlist, const float* aw1, const float* ab1,
                       const float* aw2, float* attK) {
  int blk = blockIdx.x;
  int b = blk / cG, g = blk - b * cG;
  int j = threadIdx.x;
  __shared__ float sRed[256];
  const float* sub = xlist + (g * cB + b) * 256;
  float acc = ab1[j];
  for (int i = 0; i < 256; i++) acc += sub[i] * aw1[i * 256 + j];
  if (acc < 0.0f) acc = 0.0f;
  sRed[j] = acc * aw2[j];
  __syncthreads();
  for (int s = 128; s > 0; s >>= 1) {
    if (j < s) sRed[j] += sRed[j + s];
    __syncthreads();
  }
  if (j == 0) attK[b * cG + g] = sRed[0];
}

__global__ void k_hm(const float* attK, const float* xlist, const float* mw1,
                     const float* mb1, float* metah) {
  int b = blockIdx.x;
  __shared__ float sAgg[256];
  int t = threadIdx.x;
  float a0 = attK[b * 5 + 0], a1 = attK[b * 5 + 1], a2 = attK[b * 5 + 2],
        a3 = attK[b * 5 + 3], a4 = attK[b * 5 + 4];
  float mx = a0;
  if (a1 > mx) mx = a1;
  if (a2 > mx) mx = a2;
  if (a3 > mx) mx = a3;
  if (a4 > mx) mx = a4;
  float e0 = expf(a0 - mx), e1 = expf(a1 - mx), e2 = expf(a2 - mx),
        e3 = expf(a3 - mx), e4 = expf(a4 - mx);
  float s = e0 + e1 + e2 + e3 + e4;
  sAgg[t] = (e0 * xlist[(0 * cB + b) * 256 + t] + e1 * xlist[(1 * cB + b) * 256 + t] +
             e2 * xlist[(2 * cB + b) * 256 + t] + e3 * xlist[(3 * cB + b) * 256 + t] +
             e4 * xlist[(4 * cB + b) * 256 + t]) / s;
  __syncthreads();
  for (int j = t; j < 512; j += 256) {
    float acc = mb1[j];
    for (int i = 0; i < 256; i++) acc += sAgg[i] * mw1[i * 512 + j];
    if (acc < 0.0f) acc = 0.0f;
    metah[b * 512 + j] = acc;
  }
}

__global__ void k_m2(const float* metah, const float* mw2, const float* mb2,
                     const float* xlist, const float* embout, float* xcat) {
  int i = blockIdx.x * 256 + threadIdx.x;
  if (i >= cB * 1920) return;
  int b = i / 1920, j = i - b * 1920;
  if (j < 1280) {
    float acc = mb2[j];
    const float* mh = metah + b * 512;
    for (int k = 0; k < 512; k++) acc += mh[k] * mw2[k * 1280 + j];
    int g = j >> 8, jj = j & 255;
    xcat[b * 1920 + j] = acc * xlist[(g * cB + b) * 256 + jj];
  } else {
    int jj = j - 1280;
    int g = jj >> 7, r = jj & 127;
    xcat[b * 1920 + j] = embout[(g * 100 + 2 * b + (r >> 6)) * 64 + (r & 63)];
  }
}

__global__ void k_l12(const float* xcat, const float* l1w, const float* l1b,
                      const float* l2w, const float* l2b, float* out) {
  int b = blockIdx.x;
  int t = threadIdx.x;  // 128
  __shared__ float sHH[128];
  float acc = l1b[t];
  const float* xc = xcat + b * 1920;
  for (int i = 0; i < 1920; i++) acc += xc[i] * l1w[i * 128 + t];
  if (acc < 0.0f) acc = 0.0f;
  sHH[t] = acc * l2w[t];
  __syncthreads();
  for (int s = 64; s > 0; s >>= 1) {
    if (t < s) sHH[t] += sHH[t + s];
    __syncthreads();
  }
  if (t == 0) out[b] = sHH[0] + l2b[0];
}

extern "C" void kernel_launch(void* const* d_in, const int* in_sizes, int n_in,
                              void* d_out, int out_size, void* d_ws, size_t ws_size,
                              hipStream_t stream) {
  const float* x      = (const float*)d_in[0];
  const int* ei       = (const int*)d_in[1];
  const int* et       = (const int*)d_in[2];
  const int* cen      = (const int*)d_in[3];
  const int* tt       = (const int*)d_in[4];
  const float* lab    = (const float*)d_in[5];
  const float* emb    = (const float*)d_in[6];
  const float* basis0 = (const float*)d_in[7];
  const float* comp0  = (const float*)d_in[8];
  const float* root0  = (const float*)d_in[9];
  const float* bias0  = (const float*)d_in[10];
  const float* basisR = (const float*)d_in[11];
  const float* compR  = (const float*)d_in[12];
  const float* rootR  = (const float*)d_in[13];
  const float* biasR  = (const float*)d_in[14];
  const float* pos    = (const float*)d_in[15];
  const float* Qw     = (const float*)d_in[16];
  const float* Kw     = (const float*)d_in[17];
  const float* Vw     = (const float*)d_in[18];
  const float* convW  = (const float*)d_in[19];
  const float* convb  = (const float*)d_in[20];
  const float* aw1    = (const float*)d_in[21];
  const float* ab1    = (const float*)d_in[22];
  const float* aw2    = (const float*)d_in[23];
  const float* mw1    = (const float*)d_in[24];
  const float* mb1    = (const float*)d_in[25];
  const float* mw2    = (const float*)d_in[26];
  const float* mb2    = (const float*)d_in[27];
  const float* l1w    = (const float*)d_in[28];
  const float* l1b    = (const float*)d_in[29];
  const float* l2w    = (const float*)d_in[30];
  const float* l2b    = (const float*)d_in[31];
  float* out          = (float*)d_out;

  char* p = (char*)d_ws;
  int*   uidx   = (int*)(p);                    //      2,000 B
  int*   clsb   = (int*)(p + 4096);             //    200,000 B
  int*   cur    = (int*)(p + 208896);           //  1,000,000 B (cnt -> cursor -> bin end)
  int*   off    = (int*)(p + 1212416);          //  1,000,000 B
  int*   perm   = (int*)(p + 2215936);          //  1,000,000 B (src*4 + cls)
  int*   gctr   = (int*)(p + 3219456);          //          4 B
  float* xlist  = (float*)(p + 3223552);        //    512,000 B
  float* embout = (float*)(p + 3739648);        //    128,000 B
  float* attK   = (float*)(p + 3870720);        //      1,000 B
  float* metah  = (float*)(p + 3874816);        //    102,400 B
  float* xcat   = (float*)(p + 3981312);        //    384,000 B
  char*  arena  = p + 4369408;                  // 12,800,000 B (h_a/h_b | hatt)
  float* h_a    = (float*)(arena);
  float* h_b    = (float*)(arena + 6400000);
  float* hatt   = (float*)(arena);
  (void)in_sizes; (void)n_in; (void)out_size; (void)ws_size;  // total ~17.2 MB

  k_uidx<<<cG * 2, 256, 0, stream>>>(x, uidx);

  for (int g = 0; g < cG; g++) {
    const int* eis = ei + (long long)g * 2 * cE;
    const int* eid = eis + cE;
    const int* etg = et + (long long)g * cE;
    const float* xg = x + (long long)g * cN * 4;
    // CSR build (per graph, reused across 4 layers)
    k_prep<<<977, 256, 0, stream>>>(xg, clsb, cur, gctr);
    k_histg<<<977, 256, 0, stream>>>(eid, etg, cur);
    k_mkoff<<<977, 256, 0, stream>>>(cur, off, gctr);
    k_scatter<<<977, 256, 0, stream>>>(eis, eid, etg, clsb, cur, perm);
    // layer 0
    k_gather0<<<6250, 256, 0, stream>>>(off, cur, perm, clsb, basis0, comp0,
                                        root0, bias0, h_b);
    k_extract<<<13, 256, 0, stream>>>(h_b, uidx, xlist, g, 0);
    // layers 1..3
    float* hin = h_b;
    float* hou = h_a;
    for (int l = 0; l < 3; l++) {
      k_gatherR<<<6250, 256, 0, stream>>>(off, cur, perm, hin,
                                          basisR + l * 2048, compR + l * 10,
                                          rootR + l * 1024, biasR + l * 32, hou);
      k_extract<<<13, 256, 0, stream>>>(hou, uidx, xlist, g, l + 1);
      float* tmp = hin; hin = hou; hou = tmp;
    }
  }

  for (int c = 0; c < 2; c++) {
    k_attn2<<<1000, 256, 0, stream>>>(tt, emb, pos, Qw, Kw, Vw, hatt, c * 250);
    k_convtw<<<250, 256, 0, stream>>>(hatt, tt, cen, emb, pos, convW, convb, lab,
                                      embout, c * 250);
  }

  k_att1<<<cB * cG, 256, 0, stream>>>(xlist, aw1, ab1, aw2, attK);
  k_hm<<<cB, 256, 0, stream>>>(attK, xlist, mw1, mb1, metah);
  k_m2<<<375, 256, 0, stream>>>(metah, mw2, mb2, xlist, embout, xcat);
  k_l12<<<cB, 128, 0, stream>>>(xcat, l1w, l1b, l2w, l2b, out);
}

// Round 12
// 1681.333 us; speedup vs baseline: 2.3473x; 1.2285x over previous
//
#include <hip/hip_runtime.h>
#include <hip/hip_bf16.h>

__global__ void IGMC_15247133901635_kernel() {}

#define cG 5
#define cN 50000
#define cE 250000
#define cB 50
#define cL 200
#define cD 64
#define cR 5
#define cNR 250000
#define cGB 500
#define NBLK 977

// ---------- per-graph prep: zero counts, node class ----------
__global__ void k_prep(const float* xg, int* cls, int* cur) {
  int i = blockIdx.x * 256 + threadIdx.x;  // grid = 977*256 >= cNR
  if (i < cNR) cur[i] = 0;
  if (i < cN) {
    int c = 0;
    if (xg[i * 4 + 1] == 1.0f) c = 1;
    else if (xg[i * 4 + 2] == 1.0f) c = 2;
    else if (xg[i * 4 + 3] == 1.0f) c = 3;
    cls[i] = c;
  }
}

__global__ void k_histg(const int* eid, const int* etg, int* cur) {
  int e = blockIdx.x * 256 + threadIdx.x;
  if (e < cE) atomicAdd(&cur[eid[e] * cR + etg[e]], 1);
}

// ---------- ordered global scan: block sums -> serial scan -> offsets ----------
__global__ void k_bsum(const int* cur, int* bsum) {
  __shared__ int sC[256];
  int t = threadIdx.x;
  int i = blockIdx.x * 256 + t;
  sC[t] = (i < cNR) ? cur[i] : 0;
  __syncthreads();
  for (int s = 128; s > 0; s >>= 1) {
    if (t < s) sC[t] += sC[t + s];
    __syncthreads();
  }
  if (t == 0) bsum[blockIdx.x] = sC[0];
}

__global__ void k_bscan(int* bsum) {
  if (threadIdx.x == 0 && blockIdx.x == 0) {
    int run = 0;
    for (int i = 0; i < NBLK; i++) { int v = bsum[i]; bsum[i] = run; run += v; }
  }
}

__global__ void k_mkoff(int* cur, int* off, const int* bbase) {
  __shared__ int sC[256];
  __shared__ int sO[256];
  int t = threadIdx.x;
  int i = blockIdx.x * 256 + t;
  int c = (i < cNR) ? cur[i] : 0;
  sC[t] = c;
  __syncthreads();
  if (t == 0) {
    int run = 0;
    for (int k = 0; k < 256; k++) { sO[k] = run; run += sC[k]; }
  }
  __syncthreads();
  if (i < cNR) {
    int v = bbase[blockIdx.x] + sO[t];
    off[i] = v;
    cur[i] = v;   // running cursor; after scatter cur[i] == bin end
  }
}

// perm[pos] = src*32 + r*4 + cls[src]
__global__ void k_scatter(const int* eis, const int* eid, const int* etg,
                          const int* cls, int* cur, int* perm) {
  int e = blockIdx.x * 256 + threadIdx.x;
  if (e >= cE) return;
  int src = eis[e];
  int r = etg[e];
  int bin = eid[e] * cR + r;
  int pos = atomicAdd(&cur[bin], 1);
  perm[pos] = src * 32 + r * 4 + cls[src];
}

// invc[j] = 1/count(bin containing j)
__global__ void k_invc(const int* off, const int* cur, float* invc) {
  int i = blockIdx.x * 256 + threadIdx.x;
  if (i >= cNR) return;
  int st = off[i], en = cur[i];
  if (en > st) {
    float ic = 1.0f / (float)(en - st);
    for (int j = st; j < en; j++) invc[j] = ic;
  }
}

// ---------- RGCN layer 0: flat gather of class-table rows ----------
__global__ void k_gather0(const int* off, const int* cur, const int* perm,
                          const float* invc, const int* cls, const float* basis0,
                          const float* comp0, const float* root0, const float* bias0,
                          float* hout) {
  __shared__ float sW0[640];   // [(r*4+c)*32+o]
  __shared__ float sRt[128];
  __shared__ float sB[32];
  int t = threadIdx.x;
  for (int idx = t; idx < 640; idx += 256) {
    int r = idx / 128, rem = idx - r * 128;
    sW0[idx] = comp0[r * 2] * basis0[rem] + comp0[r * 2 + 1] * basis0[128 + rem];
  }
  if (t < 128) sRt[t] = root0[t];
  if (t < 32) sB[t] = bias0[t];
  __syncthreads();
  int nd = t >> 5, li = t & 31;
  int n = blockIdx.x * 8 + nd;          // grid = 6250
  int st = off[n * 5], en = cur[n * 5 + 4];  // valid: offsets globally monotone
  float tot = 0.0f;
  int j = st;
  for (; j + 1 < en; j += 2) {
    int p0 = perm[j], p1 = perm[j + 1];
    float i0 = invc[j], i1 = invc[j + 1];
    tot += sW0[(p0 & 31) * 32 + li] * i0 + sW0[(p1 & 31) * 32 + li] * i1;
  }
  if (j < en) tot += sW0[(perm[j] & 31) * 32 + li] * invc[j];
  hout[(long long)n * 32 + li] = tanhf(tot + sRt[cls[n] * 32 + li] + sB[li]);
}

// ---------- RGCN layers 1..3: flat gather, then z_b @ B_b + h @ root ----------
__global__ void k_gatherR(const int* off, const int* cur, const int* perm,
                          const float* invc, const float* hin, const float* basis,
                          const float* comp, const float* root, const float* bias,
                          float* hout) {
  __shared__ float sB0[1024];
  __shared__ float sB1[1024];
  __shared__ float sRt[1024];
  __shared__ float sZ0[8][32];
  __shared__ float sZ1[8][32];
  __shared__ float sHl[8][32];
  __shared__ float sBias[32];
  __shared__ float sC0[8];
  __shared__ float sC1[8];
  int t = threadIdx.x;
  for (int idx = t; idx < 1024; idx += 256) {
    sB0[idx] = basis[idx];
    sB1[idx] = basis[1024 + idx];
    sRt[idx] = root[idx];
  }
  if (t < 32) sBias[t] = bias[t];
  if (t < cR) { sC0[t] = comp[t * 2]; sC1[t] = comp[t * 2 + 1]; }
  __syncthreads();
  int nd = t >> 5, li = t & 31;
  int n = blockIdx.x * 8 + nd;          // grid = 6250
  sHl[nd][li] = hin[(long long)n * 32 + li];
  int st = off[n * 5], en = cur[n * 5 + 4];  // valid: offsets globally monotone
  float z0 = 0.0f, z1 = 0.0f;
  int j = st;
  for (; j + 1 < en; j += 2) {
    int p0 = perm[j], p1 = perm[j + 1];
    float i0 = invc[j], i1 = invc[j + 1];
    float s0 = hin[(long long)(p0 >> 5) * 32 + li];
    float s1 = hin[(long long)(p1 >> 5) * 32 + li];
    int r0 = (p0 >> 2) & 7, r1 = (p1 >> 2) & 7;
    float w00 = sC0[r0] * i0, w10 = sC1[r0] * i0;
    float w01 = sC0[r1] * i1, w11 = sC1[r1] * i1;
    z0 += w00 * s0 + w01 * s1;
    z1 += w10 * s0 + w11 * s1;
  }
  if (j < en) {
    int p0 = perm[j];
    float i0 = invc[j];
    float s0 = hin[(long long)(p0 >> 5) * 32 + li];
    int r0 = (p0 >> 2) & 7;
    z0 += sC0[r0] * i0 * s0;
    z1 += sC1[r0] * i0 * s0;
  }
  sZ0[nd][li] = z0;
  sZ1[nd][li] = z1;
  __syncthreads();
  float a = sBias[li];
  for (int i = 0; i < 32; i++)
    a += sZ0[nd][i] * sB0[i * 32 + li] + sZ1[nd][i] * sB1[i * 32 + li] +
         sHl[nd][i] * sRt[i * 32 + li];
  hout[(long long)n * 32 + li] = tanhf(a);
}

// ---------- ordered compaction: first cB nodes with x[:,c]==1 ----------
__global__ void k_uidx(const float* x, int* uidx) {
  int g = blockIdx.x >> 1, c = blockIdx.x & 1;
  __shared__ int sFlag[256];
  __shared__ int sBase;
  int t = threadIdx.x;
  if (t < cB) uidx[(g * 2 + c) * cB + t] = 0;
  if (t == 0) sBase = 0;
  __syncthreads();
  for (int chunk = 0; chunk < cN; chunk += 256) {
    int n = chunk + t;
    sFlag[t] = (n < cN && x[((long long)g * cN + n) * 4 + c] == 1.0f) ? 1 : 0;
    __syncthreads();
    if (t == 0) {
      int base = sBase;
      for (int t2 = 0; t2 < 256; t2++) {
        if (sFlag[t2]) {
          if (base < cB) uidx[(g * 2 + c) * cB + base] = chunk + t2;
          base++;
        }
      }
      sBase = base;
    }
    __syncthreads();
    if (sBase >= cB) break;
  }
}

__global__ void k_extract(const float* h, const int* uidx, float* xlist, int g, int layer) {
  int i = blockIdx.x * 256 + threadIdx.x;
  if (i >= 2 * cB * 32) return;
  int o = i & 31;
  int rest = i >> 5;
  int b = rest % cB, c = rest / cB;
  int node = uidx[(g * 2 + c) * cB + b];
  xlist[(g * cB + b) * 256 + c * 128 + layer * 32 + o] = h[(long long)node * 32 + o];
}

// ---------- STAM: fused QKV + attention v4 (no-max softmax; scores tiny) ----------
__global__ void k_attn2(const int* tt, const float* emb, const float* pos,
                        const float* Qw, const float* Kw, const float* Vw,
                        float* hatt, int gb_base) {
  int gbl = blockIdx.x >> 2, hh = blockIdx.x & 3;
  int gb = gb_base + gbl;
  __shared__ float4 sQ4[800];   // 200 rows x 4 float4
  __shared__ float4 sK4[800];
  __shared__ float4 sV4[800];
  __shared__ float4 sT4[2][64];
  float* sQ = (float*)sQ4;
  float* sK = (float*)sK4;
  float* sV = (float*)sV4;
  int t = threadIdx.x;
  float wreg[64];
  int rr = t / 48, c48 = t - rr * 48;
  if (t < 192) {
    int mat = c48 >> 4, dh = c48 & 15;
    const float* W = (mat == 0) ? Qw : ((mat == 1) ? Kw : Vw);
    const float* wp = W + hh * 16 + dh;
    for (int i = 0; i < 64; i += 4) {
      wreg[i] = wp[i * 64];
      wreg[i + 1] = wp[(i + 1) * 64];
      wreg[i + 2] = wp[(i + 2) * 64];
      wreg[i + 3] = wp[(i + 3) * 64];
    }
  }
  int r4 = t >> 6, d = t & 63;
  for (int it = 0; it < 50; it++) {
    int p = it & 1;
    int l4 = it * 4 + r4;
    int idx = tt[(long long)gb * 200 + l4];
    ((float*)sT4)[p * 256 + r4 * 64 + d] =
        emb[(long long)idx * 64 + d] + pos[l4 * 64 + d];
    __syncthreads();
    if (t < 192) {
      const float4* tp = (const float4*)(sT4[p] + rr * 16);
      float acc = 0.0f;
      for (int i4 = 0; i4 < 16; i4++) {
        float4 tv = tp[i4];
        acc += tv.x * wreg[i4 * 4] + tv.y * wreg[i4 * 4 + 1] +
               tv.z * wreg[i4 * 4 + 2] + tv.w * wreg[i4 * 4 + 3];
      }
      int ll = it * 4 + rr;
      int mat = c48 >> 4, dh = c48 & 15;
      if (mat == 0) sQ[ll * 16 + dh] = acc;
      else if (mat == 1) sK[ll * 16 + dh] = acc;
      else sV[ll * 16 + dh] = acc;
    }
  }
  __syncthreads();
  if (t < 200) {
    float scale = 1.0f / sqrtf(200.0f);
    float4 q0 = sQ4[t * 4], q1 = sQ4[t * 4 + 1], q2 = sQ4[t * 4 + 2],
           q3 = sQ4[t * 4 + 3];
    q0.x *= scale; q0.y *= scale; q0.z *= scale; q0.w *= scale;
    q1.x *= scale; q1.y *= scale; q1.z *= scale; q1.w *= scale;
    q2.x *= scale; q2.y *= scale; q2.z *= scale; q2.w *= scale;
    q3.x *= scale; q3.y *= scale; q3.z *= scale; q3.w *= scale;
    float lsum = 0.0f;
    float4 o0 = {0,0,0,0}, o1 = {0,0,0,0}, o2 = {0,0,0,0}, o3 = {0,0,0,0};
    for (int m = 0; m < 200; m += 2) {
      float4 ka0 = sK4[m * 4], ka1 = sK4[m * 4 + 1], ka2 = sK4[m * 4 + 2],
             ka3 = sK4[m * 4 + 3];
      float4 kb0 = sK4[m * 4 + 4], kb1 = sK4[m * 4 + 5], kb2 = sK4[m * 4 + 6],
             kb3 = sK4[m * 4 + 7];
      float sa = q0.x * ka0.x + q0.y * ka0.y + q0.z * ka0.z + q0.w * ka0.w +
                 q1.x * ka1.x + q1.y * ka1.y + q1.z * ka1.z + q1.w * ka1.w +
                 q2.x * ka2.x + q2.y * ka2.y + q2.z * ka2.z + q2.w * ka2.w +
                 q3.x * ka3.x + q3.y * ka3.y + q3.z * ka3.z + q3.w * ka3.w;
      float sb = q0.x * kb0.x + q0.y * kb0.y + q0.z * kb0.z + q0.w * kb0.w +
                 q1.x * kb1.x + q1.y * kb1.y + q1.z * kb1.z + q1.w * kb1.w +
                 q2.x * kb2.x + q2.y * kb2.y + q2.z * kb2.z + q2.w * kb2.w +
                 q3.x * kb3.x + q3.y * kb3.y + q3.z * kb3.z + q3.w * kb3.w;
      float ea = __expf(sa);
      float eb = __expf(sb);
      float4 va0 = sV4[m * 4], va1 = sV4[m * 4 + 1], va2 = sV4[m * 4 + 2],
             va3 = sV4[m * 4 + 3];
      float4 vb0 = sV4[m * 4 + 4], vb1 = sV4[m * 4 + 5], vb2 = sV4[m * 4 + 6],
             vb3 = sV4[m * 4 + 7];
      lsum += ea + eb;
      o0.x += ea * va0.x + eb * vb0.x; o0.y += ea * va0.y + eb * vb0.y;
      o0.z += ea * va0.z + eb * vb0.z; o0.w += ea * va0.w + eb * vb0.w;
      o1.x += ea * va1.x + eb * vb1.x; o1.y += ea * va1.y + eb * vb1.y;
      o1.z += ea * va1.z + eb * vb1.z; o1.w += ea * va1.w + eb * vb1.w;
      o2.x += ea * va2.x + eb * vb2.x; o2.y += ea * va2.y + eb * vb2.y;
      o2.z += ea * va2.z + eb * vb2.z; o2.w += ea * va2.w + eb * vb2.w;
      o3.x += ea * va3.x + eb * vb3.x; o3.y += ea * va3.y + eb * vb3.y;
      o3.z += ea * va3.z + eb * vb3.z; o3.w += ea * va3.w + eb * vb3.w;
    }
    float inv = 1.0f / lsum;
    o0.x *= inv; o0.y *= inv; o0.z *= inv; o0.w *= inv;
    o1.x *= inv; o1.y *= inv; o1.z *= inv; o1.w *= inv;
    o2.x *= inv; o2.y *= inv; o2.z *= inv; o2.w *= inv;
    o3.x *= inv; o3.y *= inv; o3.z *= inv; o3.w *= inv;
    float4* outp = (float4*)(hatt + ((long long)gbl * 200 + t) * 64 + hh * 16);
    outp[0] = o0; outp[1] = o1; outp[2] = o2; outp[3] = o3;
  }
}

// ---------- STAM: conv1d + residual + L2 norm + tw-softmax + _emb ----------
__global__ void k_convtw(const float* hatt, const int* tt, const int* cen,
                         const float* emb, const float* pos, const float* convW,
                         const float* convb, const float* lab, float* embout,
                         int gb_base) {
  int gbl = blockIdx.x;
  int gb = gb_base + gbl;
  __shared__ float sH[12800];
  __shared__ float sCW[800];
  __shared__ float sA[200];
  __shared__ float sR1[256];
  __shared__ float sR2[256];
  __shared__ float sP[256];
  __shared__ float sW1[64];
  int t = threadIdx.x;
  const float* hb = hatt + (long long)gbl * 12800;
  for (int i = t; i < 12800; i += 256) sH[i] = hb[i];
  if (t < 64) sW1[t] = emb[(long long)cen[gb] * 64 + t];
  __syncthreads();
  int og = t >> 6, d = t & 63;
  for (int round = 0; round < 50; round++) {
    for (int idx = t; idx < 800; idx += 256) {
      int row = idx / 200, col = idx - row * 200;
      sCW[idx] = convW[(round * 4 + row) * 200 + col];
    }
    __syncthreads();
    int o = round * 4 + og;
    float conv = 0.0f;
    const float* cw = sCW + og * 200;
    for (int l2 = 0; l2 < 200; l2++) conv += cw[l2] * sH[l2 * 64 + d];
    float tval = emb[(long long)tt[(long long)gb * 200 + o] * 64 + d] + pos[o * 64 + d];
    float outv = tval + conv + convb[o] + sH[o * 64 + d];
    sR1[t] = outv * outv;
    sR2[t] = outv * sW1[d];
    __syncthreads();
    for (int s = 32; s > 0; s >>= 1) {
      if (d < s) { sR1[t] += sR1[t + s]; sR2[t] += sR2[t + s]; }
      __syncthreads();
    }
    if (d == 0) {
      float dn = sqrtf(sR1[t]);
      if (dn < 1e-12f) dn = 1e-12f;
      sA[o] = sR2[t] / dn;
    }
    __syncthreads();
  }
  sP[t] = (t < 200) ? sA[t] : -1e30f;
  __syncthreads();
  for (int s = 128; s > 0; s >>= 1) {
    if (t < s) { float o2 = sP[t + s]; if (o2 > sP[t]) sP[t] = o2; }
    __syncthreads();
  }
  float mx = sP[0];
  __syncthreads();
  float a = 0.0f;
  if (t < 200) {
    a = expf(sA[t] - mx) * lab[(long long)gb * 200 + t];
    sA[t] = a;
  }
  sP[t] = a;
  __syncthreads();
  for (int s = 128; s > 0; s >>= 1) {
    if (t < s) sP[t] += sP[t + s];
    __syncthreads();
  }
  float sum = sP[0];
  __syncthreads();
  if (t < 200) sA[t] = (sum > 0.0f) ? sA[t] / sum : 0.0f;
  __syncthreads();
  float acc2 = 0.0f;
  for (int l = og * 50; l < og * 50 + 50; l++)
    acc2 += sA[l] * emb[(long long)tt[(long long)gb * 200 + l] * 64 + d];
  sR1[t] = acc2;
  __syncthreads();
  if (t < 64)
    embout[(long long)gb * 64 + t] = sR1[t] + sR1[64 + t] + sR1[128 + t] + sR1[192 + t];
}

// ---------- head ----------
__global__ void k_att1(const float* xlist, const float* aw1, const float* ab1,
                       const float* aw2, float* attK) {
  int blk = blockIdx.x;
  int b = blk / cG, g = blk - b * cG;
  int j = threadIdx.x;
  __shared__ float sRed[256];
  const float* sub = xlist + (g * cB + b) * 256;
  float acc = ab1[j];
  for (int i = 0; i < 256; i++) acc += sub[i] * aw1[i * 256 + j];
  if (acc < 0.0f) acc = 0.0f;
  sRed[j] = acc * aw2[j];
  __syncthreads();
  for (int s = 128; s > 0; s >>= 1) {
    if (j < s) sRed[j] += sRed[j + s];
    __syncthreads();
  }
  if (j == 0) attK[b * cG + g] = sRed[0];
}

__global__ void k_hm(const float* attK, const float* xlist, const float* mw1,
                     const float* mb1, float* metah) {
  int b = blockIdx.x;
  __shared__ float sAgg[256];
  int t = threadIdx.x;
  float a0 = attK[b * 5 + 0], a1 = attK[b * 5 + 1], a2 = attK[b * 5 + 2],
        a3 = attK[b * 5 + 3], a4 = attK[b * 5 + 4];
  float mx = a0;
  if (a1 > mx) mx = a1;
  if (a2 > mx) mx = a2;
  if (a3 > mx) mx = a3;
  if (a4 > mx) mx = a4;
  float e0 = expf(a0 - mx), e1 = expf(a1 - mx), e2 = expf(a2 - mx),
        e3 = expf(a3 - mx), e4 = expf(a4 - mx);
  float s = e0 + e1 + e2 + e3 + e4;
  sAgg[t] = (e0 * xlist[(0 * cB + b) * 256 + t] + e1 * xlist[(1 * cB + b) * 256 + t] +
             e2 * xlist[(2 * cB + b) * 256 + t] + e3 * xlist[(3 * cB + b) * 256 + t] +
             e4 * xlist[(4 * cB + b) * 256 + t]) / s;
  __syncthreads();
  for (int j = t; j < 512; j += 256) {
    float acc = mb1[j];
    for (int i = 0; i < 256; i++) acc += sAgg[i] * mw1[i * 512 + j];
    if (acc < 0.0f) acc = 0.0f;
    metah[b * 512 + j] = acc;
  }
}

__global__ void k_m2(const float* metah, const float* mw2, const float* mb2,
                     const float* xlist, const float* embout, float* xcat) {
  int i = blockIdx.x * 256 + threadIdx.x;
  if (i >= cB * 1920) return;
  int b = i / 1920, j = i - b * 1920;
  if (j < 1280) {
    float acc = mb2[j];
    const float* mh = metah + b * 512;
    for (int k = 0; k < 512; k++) acc += mh[k] * mw2[k * 1280 + j];
    int g = j >> 8, jj = j & 255;
    xcat[b * 1920 + j] = acc * xlist[(g * cB + b) * 256 + jj];
  } else {
    int jj = j - 1280;
    int g = jj >> 7, r = jj & 127;
    xcat[b * 1920 + j] = embout[(g * 100 + 2 * b + (r >> 6)) * 64 + (r & 63)];
  }
}

__global__ void k_l12(const float* xcat, const float* l1w, const float* l1b,
                      const float* l2w, const float* l2b, float* out) {
  int b = blockIdx.x;
  int t = threadIdx.x;  // 128
  __shared__ float sHH[128];
  float acc = l1b[t];
  const float* xc = xcat + b * 1920;
  for (int i = 0; i < 1920; i++) acc += xc[i] * l1w[i * 128 + t];
  if (acc < 0.0f) acc = 0.0f;
  sHH[t] = acc * l2w[t];
  __syncthreads();
  for (int s = 64; s > 0; s >>= 1) {
    if (t < s) sHH[t] += sHH[t + s];
    __syncthreads();
  }
  if (t == 0) out[b] = sHH[0] + l2b[0];
}

extern "C" void kernel_launch(void* const* d_in, const int* in_sizes, int n_in,
                              void* d_out, int out_size, void* d_ws, size_t ws_size,
                              hipStream_t stream) {
  const float* x      = (const float*)d_in[0];
  const int* ei       = (const int*)d_in[1];
  const int* et       = (const int*)d_in[2];
  const int* cen      = (const int*)d_in[3];
  const int* tt       = (const int*)d_in[4];
  const float* lab    = (const float*)d_in[5];
  const float* emb    = (const float*)d_in[6];
  const float* basis0 = (const float*)d_in[7];
  const float* comp0  = (const float*)d_in[8];
  const float* root0  = (const float*)d_in[9];
  const float* bias0  = (const float*)d_in[10];
  const float* basisR = (const float*)d_in[11];
  const float* compR  = (const float*)d_in[12];
  const float* rootR  = (const float*)d_in[13];
  const float* biasR  = (const float*)d_in[14];
  const float* pos    = (const float*)d_in[15];
  const float* Qw     = (const float*)d_in[16];
  const float* Kw     = (const float*)d_in[17];
  const float* Vw     = (const float*)d_in[18];
  const float* convW  = (const float*)d_in[19];
  const float* convb  = (const float*)d_in[20];
  const float* aw1    = (const float*)d_in[21];
  const float* ab1    = (const float*)d_in[22];
  const float* aw2    = (const float*)d_in[23];
  const float* mw1    = (const float*)d_in[24];
  const float* mb1    = (const float*)d_in[25];
  const float* mw2    = (const float*)d_in[26];
  const float* mb2    = (const float*)d_in[27];
  const float* l1w    = (const float*)d_in[28];
  const float* l1b    = (const float*)d_in[29];
  const float* l2w    = (const float*)d_in[30];
  const float* l2b    = (const float*)d_in[31];
  float* out          = (float*)d_out;

  char* p = (char*)d_ws;
  int*   uidx   = (int*)(p);                    //      2,000 B
  int*   clsb   = (int*)(p + 4096);             //    200,000 B
  int*   cur    = (int*)(p + 208896);           //  1,000,000 B
  int*   off    = (int*)(p + 1212416);          //  1,000,000 B
  int*   perm   = (int*)(p + 2215936);          //  1,000,000 B (src*32 + r*4 + cls)
  float* invc   = (float*)(p + 3219456);        //  1,000,000 B
  int*   bsum   = (int*)(p + 4222976);          //      3,908 B
  float* xlist  = (float*)(p + 4227072);        //    512,000 B
  float* embout = (float*)(p + 4741120);        //    128,000 B
  float* attK   = (float*)(p + 4870144);        //      1,000 B
  float* metah  = (float*)(p + 4874240);        //    102,400 B
  float* xcat   = (float*)(p + 4980736);        //    384,000 B
  char*  arena  = p + 5368832;                  // 12,800,000 B (h_a/h_b | hatt)
  float* h_a    = (float*)(arena);
  float* h_b    = (float*)(arena + 6400000);
  float* hatt   = (float*)(arena);
  (void)in_sizes; (void)n_in; (void)out_size; (void)ws_size;  // total ~18.2 MB

  k_uidx<<<cG * 2, 256, 0, stream>>>(x, uidx);

  for (int g = 0; g < cG; g++) {
    const int* eis = ei + (long long)g * 2 * cE;
    const int* eid = eis + cE;
    const int* etg = et + (long long)g * cE;
    const float* xg = x + (long long)g * cN * 4;
    // CSR build with globally-ordered offsets (reused across 4 layers)
    k_prep<<<NBLK, 256, 0, stream>>>(xg, clsb, cur);
    k_histg<<<NBLK, 256, 0, stream>>>(eid, etg, cur);
    k_bsum<<<NBLK, 256, 0, stream>>>(cur, bsum);
    k_bscan<<<1, 64, 0, stream>>>(bsum);
    k_mkoff<<<NBLK, 256, 0, stream>>>(cur, off, bsum);
    k_scatter<<<NBLK, 256, 0, stream>>>(eis, eid, etg, clsb, cur, perm);
    k_invc<<<NBLK, 256, 0, stream>>>(off, cur, invc);
    // layer 0
    k_gather0<<<6250, 256, 0, stream>>>(off, cur, perm, invc, clsb, basis0, comp0,
                                        root0, bias0, h_b);
    k_extract<<<13, 256, 0, stream>>>(h_b, uidx, xlist, g, 0);
    // layers 1..3
    float* hin = h_b;
    float* hou = h_a;
    for (int l = 0; l < 3; l++) {
      k_gatherR<<<6250, 256, 0, stream>>>(off, cur, perm, invc, hin,
                                          basisR + l * 2048, compR + l * 10,
                                          rootR + l * 1024, biasR + l * 32, hou);
      k_extract<<<13, 256, 0, stream>>>(hou, uidx, xlist, g, l + 1);
      float* tmp = hin; hin = hou; hou = tmp;
    }
  }

  for (int c = 0; c < 2; c++) {
    k_attn2<<<1000, 256, 0, stream>>>(tt, emb, pos, Qw, Kw, Vw, hatt, c * 250);
    k_convtw<<<250, 256, 0, stream>>>(hatt, tt, cen, emb, pos, convW, convb, lab,
                                      embout, c * 250);
  }

  k_att1<<<cB * cG, 256, 0, stream>>>(xlist, aw1, ab1, aw2, attK);
  k_hm<<<cB, 256, 0, stream>>>(attK, xlist, mw1, mb1, metah);
  k_m2<<<375, 256, 0, stream>>>(metah, mw2, mb2, xlist, embout, xcat);
  k_l12<<<cB, 128, 0, stream>>>(xcat, l1w, l1b, l2w, l2b, out);
}